// Round 2
// baseline (1175.000 us; speedup 1.0000x reference)
//
#include <hip/hip_runtime.h>

#define DD 1024
#define KK 32

// ======================= WY-factored path =======================
// out = H - ((H V^T) M) V,  M = C diag(beta),
// C[r][j] = delta_rj - sum_{i<j} (beta_i S_ij) C[r][i],  S = V V^T.

// --- Gram: S[i][j] = dot(V_i, V_j). grid (32,32), 64 threads. ---
__global__ void gram_kernel(const float* __restrict__ V, float* __restrict__ S) {
    const int i = blockIdx.x, j = blockIdx.y;
    const int t = threadIdx.x;  // 64
    const float4* vi = (const float4*)(V + i * DD);
    const float4* vj = (const float4*)(V + j * DD);
    float s = 0.f;
    #pragma unroll
    for (int q = 0; q < 4; ++q) {
        float4 a = vi[t + (q << 6)];
        float4 b = vj[t + (q << 6)];
        s += a.x * b.x + a.y * b.y + a.z * b.z + a.w * b.w;
    }
    #pragma unroll
    for (int off = 32; off >= 1; off >>= 1) s += __shfl_xor(s, off, 64);
    if (t == 0) S[i * KK + j] = s;
}

// --- Compose: Mt[j][i] = C[i][j] / S[j][j]. One block, 64 threads. ---
__global__ void compose_kernel(const float* __restrict__ S, float* __restrict__ Mt) {
    const int r = threadIdx.x;       // lane r holds row r of C (r<32 active)
    float C[KK];
    #pragma unroll
    for (int j = 0; j < KK; ++j) {
        float acc = (r == j) ? 1.f : 0.f;
        #pragma unroll
        for (int i = 0; i < j; ++i) {
            float coef = S[i * KK + j] / S[i * KK + i];  // beta_i * S_ij, uniform
            acc -= coef * C[i];
        }
        C[j] = acc;
        if (r < KK) Mt[j * KK + r] = acc / S[j * KK + j];
    }
}

// --- Dots: U[n][k] += dot(H_n[quarter], V_k[quarter]). lane = node. ---
// 4 waves/block; wave = (node-group ng, d-quarter q). V via scalar loads.
__global__ __launch_bounds__(256, 4) void dots_kernel(
    const float* __restrict__ H, const float* __restrict__ V,
    float* __restrict__ U) {
    const int lane = threadIdx.x & 63;
    const int wid  = threadIdx.x >> 6;
    const int gw   = (blockIdx.x << 2) + wid;
    const int ng   = gw >> 2;
    const int q    = __builtin_amdgcn_readfirstlane(gw & 3);  // wave-uniform
    const int n    = (ng << 6) + lane;

    const float* hrow = H + (size_t)n * DD + (q << 8);
    float u[KK];
    #pragma unroll
    for (int k = 0; k < KK; ++k) u[k] = 0.f;

    for (int c = 0; c < 8; ++c) {            // 8 chunks x 32 floats = 256 (quarter)
        const int dbase = c << 5;
        float4 h4[8];
        #pragma unroll
        for (int x = 0; x < 8; ++x) h4[x] = *(const float4*)(hrow + dbase + (x << 2));
        const float* vb = V + (q << 8) + dbase;   // wave-uniform base
        #pragma unroll
        for (int k = 0; k < KK; ++k) {
            const float* vk = vb + k * DD;        // uniform -> s_load
            #pragma unroll
            for (int x = 0; x < 8; ++x) {
                u[k] = fmaf(h4[x].x, vk[(x << 2) + 0], u[k]);
                u[k] = fmaf(h4[x].y, vk[(x << 2) + 1], u[k]);
                u[k] = fmaf(h4[x].z, vk[(x << 2) + 2], u[k]);
                u[k] = fmaf(h4[x].w, vk[(x << 2) + 3], u[k]);
            }
        }
    }
    float* up = U + ((size_t)n << 5);
    #pragma unroll
    for (int k = 0; k < KK; ++k) atomicAdd(up + k, u[k]);
}

// --- Update: g = u . Mt rows; out = h - sum_j g_j V_j. lane = node. ---
__global__ __launch_bounds__(256, 4) void update_kernel(
    const float* __restrict__ H, const float* __restrict__ V,
    const float* __restrict__ U, const float* __restrict__ Mt,
    float* __restrict__ out) {
    const int lane = threadIdx.x & 63;
    const int wid  = threadIdx.x >> 6;
    const int gw   = (blockIdx.x << 2) + wid;
    const int ng   = gw >> 2;
    const int q    = __builtin_amdgcn_readfirstlane(gw & 3);
    const int n    = (ng << 6) + lane;

    float uu[KK];
    {
        const float4* up = (const float4*)(U + ((size_t)n << 5));
        #pragma unroll
        for (int x = 0; x < 8; ++x) {
            float4 t4 = up[x];
            uu[(x << 2) + 0] = t4.x; uu[(x << 2) + 1] = t4.y;
            uu[(x << 2) + 2] = t4.z; uu[(x << 2) + 3] = t4.w;
        }
    }
    float g[KK];
    #pragma unroll
    for (int j = 0; j < KK; ++j) {
        const float* mr = Mt + j * KK;            // uniform -> s_load
        float a = 0.f;
        #pragma unroll
        for (int i = 0; i < KK; ++i) a = fmaf(uu[i], mr[i], a);
        g[j] = a;
    }

    const float* hrow = H + (size_t)n * DD + (q << 8);
    float*       orow = out + (size_t)n * DD + (q << 8);
    for (int c = 0; c < 8; ++c) {
        const int dbase = c << 5;
        float4 h4[8];
        #pragma unroll
        for (int x = 0; x < 8; ++x) h4[x] = *(const float4*)(hrow + dbase + (x << 2));
        const float* vb = V + (q << 8) + dbase;
        #pragma unroll
        for (int j = 0; j < KK; ++j) {
            const float* vj = vb + j * DD;        // uniform -> s_load
            const float gj = g[j];
            #pragma unroll
            for (int x = 0; x < 8; ++x) {
                h4[x].x = fmaf(-gj, vj[(x << 2) + 0], h4[x].x);
                h4[x].y = fmaf(-gj, vj[(x << 2) + 1], h4[x].y);
                h4[x].z = fmaf(-gj, vj[(x << 2) + 2], h4[x].z);
                h4[x].w = fmaf(-gj, vj[(x << 2) + 3], h4[x].w);
            }
        }
        #pragma unroll
        for (int x = 0; x < 8; ++x) *(float4*)(orow + dbase + (x << 2)) = h4[x];
    }
}

// ======================= Fallback path (R1, proven) =======================
__global__ void vv_inv_kernel(const float* __restrict__ V, float* __restrict__ vvinv) {
    int k = blockIdx.x;
    const float* v = V + k * DD;
    int t = threadIdx.x;
    float s = 0.f;
    for (int i = t; i < DD; i += 256) { float x = v[i]; s += x * x; }
    #pragma unroll
    for (int off = 32; off >= 1; off >>= 1) s += __shfl_xor(s, off, 64);
    __shared__ float red[4];
    if ((t & 63) == 0) red[t >> 6] = s;
    __syncthreads();
    if (t == 0) vvinv[k] = 1.0f / (red[0] + red[1] + red[2] + red[3]);
}

__global__ __launch_bounds__(1024) void hh_tower_kernel(
    const float* __restrict__ H, const float* __restrict__ V,
    const float* __restrict__ vvinv, float* __restrict__ out, int Nn)
{
    extern __shared__ float Vl[];
    {
        const float4* src = (const float4*)V;
        float4* dst = (float4*)Vl;
        int t = threadIdx.x;
        #pragma unroll
        for (int i = 0; i < 8; ++i) dst[t + (i << 10)] = src[t + (i << 10)];
    }
    __syncthreads();
    const int lane = threadIdx.x & 63;
    const int wid  = threadIdx.x >> 6;
    const int gwave  = blockIdx.x * (blockDim.x >> 6) + wid;
    const int nwaves = gridDim.x * (blockDim.x >> 6);
    const int s  = (lane >> 2) & 1;
    const int o0 = (lane << 3) + (s << 2);
    const int o1 = (lane << 3) + ((1 - s) << 2);
    const int o2 = 512 + o0;
    const int o3 = 512 + o1;
    const int ngroups = Nn >> 2;
    for (int g = gwave; g < ngroups; g += nwaves) {
        const int base = g << 2;
        float4 h0[4], h1[4], h2[4], h3[4];
        #pragma unroll
        for (int m = 0; m < 4; ++m) {
            const float* row = H + (size_t)(base + m) * DD;
            h0[m] = *(const float4*)(row + o0);
            h1[m] = *(const float4*)(row + o1);
            h2[m] = *(const float4*)(row + o2);
            h3[m] = *(const float4*)(row + o3);
        }
        #pragma unroll 2
        for (int k = 0; k < KK; ++k) {
            const float* vr = Vl + (k << 10);
            const float4 v0 = *(const float4*)(vr + o0);
            const float4 v1 = *(const float4*)(vr + o1);
            const float4 v2 = *(const float4*)(vr + o2);
            const float4 v3 = *(const float4*)(vr + o3);
            const float vi = vvinv[k];
            float dot[4];
            #pragma unroll
            for (int m = 0; m < 4; ++m) {
                float pa = h0[m].x * v0.x + h0[m].y * v0.y + h0[m].z * v0.z + h0[m].w * v0.w;
                float pb = h1[m].x * v1.x + h1[m].y * v1.y + h1[m].z * v1.z + h1[m].w * v1.w;
                float pc = h2[m].x * v2.x + h2[m].y * v2.y + h2[m].z * v2.z + h2[m].w * v2.w;
                float pd = h3[m].x * v3.x + h3[m].y * v3.y + h3[m].z * v3.z + h3[m].w * v3.w;
                dot[m] = (pa + pb) + (pc + pd);
            }
            #pragma unroll
            for (int off = 1; off <= 32; off <<= 1) {
                #pragma unroll
                for (int m = 0; m < 4; ++m) dot[m] += __shfl_xor(dot[m], off, 64);
            }
            #pragma unroll
            for (int m = 0; m < 4; ++m) {
                const float gc = dot[m] * vi;
                h0[m].x -= gc * v0.x; h0[m].y -= gc * v0.y; h0[m].z -= gc * v0.z; h0[m].w -= gc * v0.w;
                h1[m].x -= gc * v1.x; h1[m].y -= gc * v1.y; h1[m].z -= gc * v1.z; h1[m].w -= gc * v1.w;
                h2[m].x -= gc * v2.x; h2[m].y -= gc * v2.y; h2[m].z -= gc * v2.z; h2[m].w -= gc * v2.w;
                h3[m].x -= gc * v3.x; h3[m].y -= gc * v3.y; h3[m].z -= gc * v3.z; h3[m].w -= gc * v3.w;
            }
        }
        #pragma unroll
        for (int m = 0; m < 4; ++m) {
            float* row = out + (size_t)(base + m) * DD;
            *(float4*)(row + o0) = h0[m];
            *(float4*)(row + o1) = h1[m];
            *(float4*)(row + o2) = h2[m];
            *(float4*)(row + o3) = h3[m];
        }
    }
}

// ======================= Launch =======================
extern "C" void kernel_launch(void* const* d_in, const int* in_sizes, int n_in,
                              void* d_out, int out_size, void* d_ws, size_t ws_size,
                              hipStream_t stream) {
    const float* H = (const float*)d_in[0];   // [N, 1024] fp32
    const float* V = (const float*)d_in[1];   // [32, 1024] fp32
    float* out = (float*)d_out;
    const int Nn = in_sizes[0] / DD;          // 65536

    const size_t U_bytes  = (size_t)Nn * KK * sizeof(float);     // 8 MB
    const size_t need     = U_bytes + 2 * KK * KK * sizeof(float);

    if (ws_size >= need) {
        float* U  = (float*)d_ws;
        float* S  = (float*)((char*)d_ws + U_bytes);
        float* Mt = S + KK * KK;

        hipMemsetAsync(U, 0, U_bytes, stream);
        gram_kernel<<<dim3(KK, KK), 64, 0, stream>>>(V, S);
        compose_kernel<<<1, 64, 0, stream>>>(S, Mt);
        const int nblocks = Nn >> 6;          // 1024: 4 waves = 4 d-quarters/group
        dots_kernel<<<nblocks, 256, 0, stream>>>(H, V, U);
        update_kernel<<<nblocks, 256, 0, stream>>>(H, V, U, Mt, out);
    } else {
        // Fallback: proven R1 path (needs only 128 B of ws).
        float* vvinv = (float*)d_ws;
        vv_inv_kernel<<<KK, 256, 0, stream>>>(V, vvinv);
        const int smem = KK * DD * (int)sizeof(float);
        hipFuncSetAttribute((const void*)hh_tower_kernel,
                            hipFuncAttributeMaxDynamicSharedMemorySize, smem);
        hh_tower_kernel<<<256, 1024, smem, stream>>>(H, V, vvinv, out, Nn);
    }
}